// Round 14
// baseline (583.380 us; speedup 1.0000x reference)
//
#include <hip/hip_runtime.h>
#include <hip/hip_bf16.h>

// Problem constants (fixed by reference)
#define NN 100000
#define EE 1600000
#define HH 128
#define NB 391      // buckets = ceil(NN/256)
#define CAP 5120    // padded bucket capacity (mean 4096, sigma 64 -> +16 sigma)

typedef short bf16x8 __attribute__((ext_vector_type(8)));
typedef short bf16x4 __attribute__((ext_vector_type(4)));
typedef float f32x4  __attribute__((ext_vector_type(4)));

__device__ inline short f2bf(float v) {
    __hip_bfloat16 b = __float2bfloat16(v);
    return *reinterpret_cast<short*>(&b);
}

// ---------------------------------------------------------------------------
// zero the 391 bucket cursors
// ---------------------------------------------------------------------------
__global__ __launch_bounds__(512) void zerob_kernel(int* __restrict__ bcur) {
    if (threadIdx.x < NB) bcur[threadIdx.x] = 0;
}

// ---------------------------------------------------------------------------
// Phase 1 (+ independent weight prep fused as extra blocks):
// blocks [0,NB): bucket-partition edges by dst>>8. blocks [NB,NB+128): WT prep.
// ---------------------------------------------------------------------------
__global__ __launch_bounds__(1024) void scatter_prepw_kernel(
    const int* __restrict__ srcv, const int* __restrict__ dstv,
    int* __restrict__ bcur, int* __restrict__ pairs,
    const float* __restrict__ Wl0, const float* __restrict__ Wr0,
    const float* __restrict__ Wl1, const float* __restrict__ Wr1,
    const float* __restrict__ Wl2, const float* __restrict__ Wr2,
    __hip_bfloat16* __restrict__ WT0, __hip_bfloat16* __restrict__ WT1,
    __hip_bfloat16* __restrict__ WT2) {
    __shared__ int hist[NB];
    __shared__ int base[NB];
    const int t = threadIdx.x;

    if (blockIdx.x >= NB) {                      // ---- prepw branch ----
        int id = (blockIdx.x - NB) * 1024 + t;   // 0 .. 131071
        if (id < 65536) {                        // layer 0: K=256
            int k = id & 255, n = id >> 8;
            float v = (n < 128) ? Wl0[(size_t)k * 128 + n]
                                : Wr0[(size_t)k * 128 + (n - 128)];
            WT0[(size_t)n * 256 + k] = __float2bfloat16(v);
        } else {
            id -= 65536;
            int layer = id >> 15;                // 0 -> L1, 1 -> L2
            int u = id & 32767;
            int k = u & 127, n = u >> 7;
            const float* Wl = layer ? Wl2 : Wl1;
            const float* Wr = layer ? Wr2 : Wr1;
            __hip_bfloat16* WT = layer ? WT2 : WT1;
            float v = (n < 128) ? Wl[(size_t)k * 128 + n]
                                : Wr[(size_t)k * 128 + (n - 128)];
            WT[(size_t)n * 128 + k] = __float2bfloat16(v);
        }
        return;
    }

    // ---- scatter branch ----
    for (int j = t; j < NB; j += 1024) hist[j] = 0;
    __syncthreads();

    const int e0 = blockIdx.x * 4096;
    int s[4], d[4], n = 0;
#pragma unroll
    for (int u = 0; u < 4; ++u) {
        int e = e0 + u * 1024 + t;
        if (e < EE) { s[n] = srcv[e]; d[n] = dstv[e]; ++n; }
    }
#pragma unroll
    for (int u = 0; u < 4; ++u)
        if (u < n) atomicAdd(&hist[d[u] >> 8], 1);
    __syncthreads();

    for (int j = t; j < NB; j += 1024)
        base[j] = hist[j] ? atomicAdd(&bcur[j], hist[j]) : 0;
    __syncthreads();
    for (int j = t; j < NB; j += 1024) hist[j] = base[j];   // reuse as cursor
    __syncthreads();

#pragma unroll
    for (int u = 0; u < 4; ++u)
        if (u < n) {
            const int b   = d[u] >> 8;
            const int pos = atomicAdd(&hist[b], 1);
            if (pos < CAP) pairs[b * CAP + pos] = (s[u] << 8) | (d[u] & 255);
        }
}

// ---------------------------------------------------------------------------
// Phase 2: per-bucket counting sort -> csr grouped by node + beg/end/inv.
// ---------------------------------------------------------------------------
__global__ __launch_bounds__(256) void finalize_kernel(
    const int* __restrict__ bcur, const int* __restrict__ pairs,
    int* __restrict__ csr, int* __restrict__ beg, int* __restrict__ eend,
    float* __restrict__ inv) {
    __shared__ int cnt[256];
    __shared__ int scn[256];
    __shared__ int cur[256];
    const int b = blockIdx.x, t = threadIdx.x;
    int m = bcur[b];
    if (m > CAP) m = CAP;

    cnt[t] = 0;
    __syncthreads();
    for (int e = t; e < m; e += 256)
        atomicAdd(&cnt[pairs[b * CAP + e] & 255], 1);
    __syncthreads();

    const int v = cnt[t];
    scn[t] = v;
    __syncthreads();
    for (int st = 1; st < 256; st <<= 1) {
        int tv = (t >= st) ? scn[t - st] : 0;
        __syncthreads();
        scn[t] += tv;
        __syncthreads();
    }
    const int myStart = scn[t] - v;          // exclusive scan
    cur[t] = myStart;
    __syncthreads();

    for (int e = t; e < m; e += 256) {
        const int pk  = pairs[b * CAP + e];
        const int pos = atomicAdd(&cur[pk & 255], 1);
        csr[b * CAP + pos] = pk >> 8;
    }

    const int node = b * 256 + t;
    if (node < NN) {
        beg[node]  = b * CAP + myStart;
        eend[node] = b * CAP + myStart + v;
        inv[node]  = 1.0f / fmaxf((float)v, 1.0f);
    }
}

// ---------------------------------------------------------------------------
// MFMA GEMM, BARRIER-FREE (round 14): [z | r] = h @ [Wl | Wr] (+b on r).
// Each wave is self-contained: owns 32 nodes x 128 outputs (w0/w1 = z for
// node halves, w2/w3 = r). B-fragments = the wave's OWN h-rows direct from
// global (each row read once per block; no staging, no cross-wave sharing).
// A = weight rows from L2 (2x intra-block redundancy - trivial vs 34.5TB/s).
// Epilogue transposes through a PER-WAVE private LDS region (16x136 halves,
// in-wave lgkmcnt ordering only). Zero __syncthreads: round-12's 6 barrier-
// drained phases were the gemm bottleneck (67us vs 17us traffic floor);
// round-13 showed smaller tiles make the per-output overhead worse.
// zout is a DEDICATED buffer (never aliases hin) -> no cross-wave hazard.
// ---------------------------------------------------------------------------
#define TW2 136   // per-wave LDS row stride in halves (272 B, 16B-aligned)
template <int K, bool FIRST>
__global__ __launch_bounds__(256) void gemm_kernel(
    const __hip_bfloat16* __restrict__ hin,
    const float* __restrict__ x0, const float* __restrict__ x1,
    const float* __restrict__ x2, const float* __restrict__ x3,
    const __hip_bfloat16* __restrict__ wt, const float* __restrict__ bias,
    __hip_bfloat16* __restrict__ zout, __hip_bfloat16* __restrict__ rout) {
    __shared__ short lsh[4 * 16 * TW2];        // 17408 B, one region per wave
    const int t    = threadIdx.x;
    const int w    = t >> 6;
    const int lane = t & 63;
    const int quad = lane >> 4;
    const int l16  = lane & 15;
    const bool isr = (w >= 2);
    const int n0   = blockIdx.x * 64;
    const int nb   = n0 + (w & 1) * 32;        // this wave's 32-node base

    // A: weight feature rows (z-waves: Wl rows 0..127; r-waves: Wr 128..255)
    const __hip_bfloat16* abase = wt + (size_t)((isr ? 128 : 0) + l16) * K + quad * 8;

    int node[2];
#pragma unroll
    for (int nt = 0; nt < 2; ++nt) {
        int n = nb + nt * 16 + l16;
        node[nt] = (n > NN - 1) ? (NN - 1) : n;   // clamp (stores are guarded)
    }

    f32x4 acc[8][2];
#pragma unroll
    for (int ft = 0; ft < 8; ++ft)
#pragma unroll
        for (int nt = 0; nt < 2; ++nt)
            acc[ft][nt] = (f32x4){0.f, 0.f, 0.f, 0.f};

#pragma unroll
    for (int kc = 0; kc < K / 32; ++kc) {
        bf16x8 af[8];
#pragma unroll
        for (int ft = 0; ft < 8; ++ft)
            af[ft] = *(const bf16x8*)(abase + (size_t)(ft * 16) * K + kc * 32);

        bf16x8 bf[2];
        if (FIRST) {
            const float* s = (kc < 2) ? x0 : (kc < 4) ? x1 : (kc < 6) ? x2 : x3;
            const int scol = (kc & 1) * 32 + quad * 8;
#pragma unroll
            for (int nt = 0; nt < 2; ++nt) {
                const float4 v0 = *(const float4*)&s[(size_t)node[nt] * 64 + scol];
                const float4 v1 = *(const float4*)&s[(size_t)node[nt] * 64 + scol + 4];
                bf16x8 bb;
                bb[0] = f2bf(v0.x); bb[1] = f2bf(v0.y);
                bb[2] = f2bf(v0.z); bb[3] = f2bf(v0.w);
                bb[4] = f2bf(v1.x); bb[5] = f2bf(v1.y);
                bb[6] = f2bf(v1.z); bb[7] = f2bf(v1.w);
                bf[nt] = bb;
            }
        } else {
#pragma unroll
            for (int nt = 0; nt < 2; ++nt)
                bf[nt] = *(const bf16x8*)(hin + (size_t)node[nt] * K + kc * 32 + quad * 8);
        }

#pragma unroll
        for (int ft = 0; ft < 8; ++ft)
#pragma unroll
            for (int nt = 0; nt < 2; ++nt)
                acc[ft][nt] = __builtin_amdgcn_mfma_f32_16x16x32_bf16(
                    af[ft], bf[nt], acc[ft][nt], 0, 0, 0);
    }

    // ---- per-wave epilogue: transpose via private LDS region, no barriers.
    // D: col = lane&15 = node, row = quad*4+reg = feature  [m89 verified]
    short* reg = lsh + w * 16 * TW2;
    __hip_bfloat16* outp = isr ? rout : zout;
#pragma unroll
    for (int p = 0; p < 2; ++p) {              // node half nt = p
#pragma unroll
        for (int ft = 0; ft < 8; ++ft) {
            const int fb = ft * 16 + quad * 4;
            float4 bv = make_float4(0.f, 0.f, 0.f, 0.f);
            if (isr) bv = *(const float4*)&bias[fb];
            const f32x4 a = acc[ft][p];
            bf16x4 q;
            q[0] = f2bf(a[0] + bv.x); q[1] = f2bf(a[1] + bv.y);
            q[2] = f2bf(a[2] + bv.z); q[3] = f2bf(a[3] + bv.w);
            *(bf16x4*)&reg[l16 * TW2 + fb] = q;
        }
        // in-wave read-back: 16 lanes = one full 256B node row
#pragma unroll
        for (int u = 0; u < 4; ++u) {
            const int row = u * 4 + quad;      // 0..15 within this half
            const int ch  = l16 * 8;
            const int g   = nb + p * 16 + row;
            const bf16x8 v = *(const bf16x8*)&reg[row * TW2 + ch];
            if (g < NN)
                *(bf16x8*)&outp[(size_t)g * HH + ch] = v;
        }
    }
}

// ---------------------------------------------------------------------------
// Aggregation + combine: h_out = relu(mean_{in-edges}(z[src]) + r)
// One wave per node; 4 groups x 16 lanes; 16B loads; 4x unroll -> all ~16
// gathers of a mean-degree node in flight. Butterfly (xor 16,32) at the end.
// LAST: fuse layer-3 projection (h3 in f32 regs -> dot Wl3/Wr3 -> z3/r3).
// ---------------------------------------------------------------------------
template <bool LAST>
__global__ __launch_bounds__(256) void aggregate_kernel(
    const __hip_bfloat16* __restrict__ z, __hip_bfloat16* __restrict__ rio,
    const int* __restrict__ beg, const int* __restrict__ eend,
    const int* __restrict__ csr, const float* __restrict__ inv,
    const float* __restrict__ Wl3, const float* __restrict__ Wr3,
    const float* __restrict__ b3, float* __restrict__ z3,
    float* __restrict__ r3) {
    const int i    = (blockIdx.x * 256 + threadIdx.x) >> 6;
    const int lane = threadIdx.x & 63;
    const int g    = lane >> 4;          // edge slot 0..3
    const int l16  = lane & 15;          // 16B chunk within the z row
    if (i >= NN) return;
    const int b0 = beg[i], e0 = eend[i];

    float acc[8];
#pragma unroll
    for (int j = 0; j < 8; ++j) acc[j] = 0.f;

    int e = b0 + g;
    for (; e + 12 < e0; e += 16) {
        const int s0 = csr[e];
        const int s1 = csr[e + 4];
        const int s2 = csr[e + 8];
        const int s3 = csr[e + 12];
        const bf16x8 z0 = *(const bf16x8*)&z[(size_t)s0 * HH + l16 * 8];
        const bf16x8 z1 = *(const bf16x8*)&z[(size_t)s1 * HH + l16 * 8];
        const bf16x8 z2 = *(const bf16x8*)&z[(size_t)s2 * HH + l16 * 8];
        const bf16x8 z3v = *(const bf16x8*)&z[(size_t)s3 * HH + l16 * 8];
        const __hip_bfloat162* p0 = (const __hip_bfloat162*)&z0;
        const __hip_bfloat162* p1 = (const __hip_bfloat162*)&z1;
        const __hip_bfloat162* p2 = (const __hip_bfloat162*)&z2;
        const __hip_bfloat162* p3 = (const __hip_bfloat162*)&z3v;
#pragma unroll
        for (int j = 0; j < 4; ++j) {
            acc[2 * j]     += __bfloat162float(p0[j].x) + __bfloat162float(p1[j].x)
                            + __bfloat162float(p2[j].x) + __bfloat162float(p3[j].x);
            acc[2 * j + 1] += __bfloat162float(p0[j].y) + __bfloat162float(p1[j].y)
                            + __bfloat162float(p2[j].y) + __bfloat162float(p3[j].y);
        }
    }
    for (; e < e0; e += 4) {
        const int s0 = csr[e];
        const bf16x8 z0 = *(const bf16x8*)&z[(size_t)s0 * HH + l16 * 8];
        const __hip_bfloat162* p0 = (const __hip_bfloat162*)&z0;
#pragma unroll
        for (int j = 0; j < 4; ++j) {
            acc[2 * j]     += __bfloat162float(p0[j].x);
            acc[2 * j + 1] += __bfloat162float(p0[j].y);
        }
    }

#pragma unroll
    for (int j = 0; j < 8; ++j) {
        acc[j] += __shfl_xor(acc[j], 16, 64);
        acc[j] += __shfl_xor(acc[j], 32, 64);
    }

    const float iv = inv[i];
    const int   f  = l16 * 8 + g * 2;
    const __hip_bfloat162 rv = *(const __hip_bfloat162*)&rio[(size_t)i * HH + f];
    const float ox = fmaxf(acc[g * 2]     * iv + __bfloat162float(rv.x), 0.f);
    const float oy = fmaxf(acc[g * 2 + 1] * iv + __bfloat162float(rv.y), 0.f);

    if (!LAST) {
        __hip_bfloat162 o;
        o.x = __float2bfloat16(ox);
        o.y = __float2bfloat16(oy);
        *(__hip_bfloat162*)&rio[(size_t)i * HH + f] = o;
    } else {
        const float2 wl = *(const float2*)&Wl3[f];
        const float2 wr = *(const float2*)&Wr3[f];
        float al = ox * wl.x + oy * wl.y;
        float ar = ox * wr.x + oy * wr.y;
#pragma unroll
        for (int m = 32; m; m >>= 1) {
            al += __shfl_xor(al, m, 64);
            ar += __shfl_xor(ar, m, 64);
        }
        if (lane == 0) {
            z3[i] = al;
            r3[i] = ar + b3[0];
        }
    }
}

// Final: out[i] = sigmoid(mean(z3[src]) + r3[i]); per-block partial sums
__global__ __launch_bounds__(256) void final_kernel(
    const float* __restrict__ z3, const float* __restrict__ r3,
    const int* __restrict__ beg, const int* __restrict__ eend,
    const int* __restrict__ csr, const float* __restrict__ inv,
    float* __restrict__ out, float* __restrict__ partial) {
    __shared__ float red[4];
    const int i    = (blockIdx.x * 256 + threadIdx.x) >> 6;
    const int lane = threadIdx.x & 63;
    const int w    = threadIdx.x >> 6;
    float v = 0.f;
    if (i < NN) {
        const int b0 = beg[i], e0 = eend[i];
        float a = 0.f;
        for (int e = b0 + lane; e < e0; e += 64) a += z3[csr[e]];
#pragma unroll
        for (int m = 32; m; m >>= 1) a += __shfl_xor(a, m, 64);
        const float pre = a * inv[i] + r3[i];
        const float s = 1.f / (1.f + __expf(-pre));
        if (lane == 0) { out[i] = s; v = s; }
    }
    if (lane == 0) red[w] = v;
    __syncthreads();
    if (threadIdx.x == 0)
        partial[blockIdx.x] = red[0] + red[1] + red[2] + red[3];
}

__global__ __launch_bounds__(256) void mean_kernel(const float* __restrict__ partial,
                                                   int nb, float* __restrict__ out) {
    __shared__ float lds[256];
    float s = 0.f;
    for (int i = threadIdx.x; i < nb; i += 256) s += partial[i];
    lds[threadIdx.x] = s;
    __syncthreads();
    for (int st = 128; st; st >>= 1) {
        if (threadIdx.x < st) lds[threadIdx.x] += lds[threadIdx.x + st];
        __syncthreads();
    }
    if (threadIdx.x == 0) out[NN] = lds[0] / (float)NN;
}

// ---------------------------------------------------------------------------
extern "C" void kernel_launch(void* const* d_in, const int* in_sizes, int n_in,
                              void* d_out, int out_size, void* d_ws, size_t ws_size,
                              hipStream_t stream) {
    const float* x    = (const float*)d_in[0];
    const float* diff = (const float*)d_in[1];
    const float* rec  = (const float*)d_in[2];
    const float* hid  = (const float*)d_in[3];
    const int* edge   = (const int*)d_in[4];
    const int* esrc = edge;        // row 0
    const int* edst = edge + EE;   // row 1
    const float* Wl0 = (const float*)d_in[5];
    const float* Wr0 = (const float*)d_in[6];
    const float* b0  = (const float*)d_in[7];
    const float* Wl1 = (const float*)d_in[8];
    const float* Wr1 = (const float*)d_in[9];
    const float* b1  = (const float*)d_in[10];
    const float* Wl2 = (const float*)d_in[11];
    const float* Wr2 = (const float*)d_in[12];
    const float* b2  = (const float*)d_in[13];
    const float* Wl3 = (const float*)d_in[14];
    const float* Wr3 = (const float*)d_in[15];
    const float* b3  = (const float*)d_in[16];
    float* out = (float*)d_out;

    // workspace carve-out (256B aligned) — total ~95 MB
    char* w = (char*)d_ws;
    auto alloc = [&](size_t bytes) -> void* {
        void* p = (void*)w;
        w += (bytes + 255) & ~(size_t)255;
        return p;
    };
    __hip_bfloat16* bufA = (__hip_bfloat16*)alloc((size_t)NN * HH * 2);  // 25.6 MB
    __hip_bfloat16* bufB = (__hip_bfloat16*)alloc((size_t)NN * HH * 2);  // 25.6 MB
    __hip_bfloat16* bufZ = (__hip_bfloat16*)alloc((size_t)NN * HH * 2);  // 25.6 MB
    __hip_bfloat16* WT0  = (__hip_bfloat16*)alloc((size_t)256 * 256 * 2);
    __hip_bfloat16* WT1  = (__hip_bfloat16*)alloc((size_t)256 * 128 * 2);
    __hip_bfloat16* WT2  = (__hip_bfloat16*)alloc((size_t)256 * 128 * 2);
    int*   pairs   = (int*)alloc((size_t)NB * CAP * 4);                  // 8.0 MB
    int*   csr     = (int*)alloc((size_t)NB * CAP * 4);                  // 8.0 MB
    int*   bcur    = (int*)alloc((size_t)512 * 4);
    int*   beg     = (int*)alloc((size_t)NN * 4);
    int*   eend    = (int*)alloc((size_t)NN * 4);
    float* inv     = (float*)alloc((size_t)NN * 4);
    float* z3      = (float*)alloc((size_t)NN * 4);
    float* r3      = (float*)alloc((size_t)NN * 4);
    float* partial = (float*)alloc((size_t)25000 * 4);

    const int GB  = (NN + 63) / 64;          // 1563 (MFMA gemm blocks)
    const int WB  = (NN + 3) / 4;            // 25000 (1 node/wave)

    // CSR build (binned) + weight prep fused into scatter's launch
    zerob_kernel<<<1, 512, 0, stream>>>(bcur);
    scatter_prepw_kernel<<<NB + 128, 1024, 0, stream>>>(
        esrc, edst, bcur, pairs, Wl0, Wr0, Wl1, Wr1, Wl2, Wr2, WT0, WT1, WT2);
    finalize_kernel<<<NB, 256, 0, stream>>>(bcur, pairs, csr, beg, eend, inv);

    // L0: K=256, fused f32 concat+convert; z -> Z, r -> A; agg: h1 -> A
    gemm_kernel<256, true><<<GB, 256, 0, stream>>>(nullptr, x, diff, rec, hid,
                                                   WT0, b0, bufZ, bufA);
    aggregate_kernel<false><<<WB, 256, 0, stream>>>(bufZ, bufA, beg, eend, csr, inv,
                                                    nullptr, nullptr, nullptr,
                                                    nullptr, nullptr);

    // L1: h in A; z -> Z, r -> B; agg: h2 -> B
    gemm_kernel<128, false><<<GB, 256, 0, stream>>>(bufA, nullptr, nullptr, nullptr, nullptr,
                                                    WT1, b1, bufZ, bufB);
    aggregate_kernel<false><<<WB, 256, 0, stream>>>(bufZ, bufB, beg, eend, csr, inv,
                                                    nullptr, nullptr, nullptr,
                                                    nullptr, nullptr);

    // L2: h in B; z -> Z, r -> A; agg(LAST): fused proj3 -> z3, r3
    gemm_kernel<128, false><<<GB, 256, 0, stream>>>(bufB, nullptr, nullptr, nullptr, nullptr,
                                                    WT2, b2, bufZ, bufA);
    aggregate_kernel<true><<<WB, 256, 0, stream>>>(bufZ, bufA, beg, eend, csr, inv,
                                                   Wl3, Wr3, b3, z3, r3);

    // final: aggregate scalars, sigmoid + mean
    final_kernel<<<WB, 256, 0, stream>>>(z3, r3, beg, eend, csr, inv, out, partial);
    mean_kernel<<<1, 256, 0, stream>>>(partial, WB, out);
}

// Round 15
// 512.774 us; speedup vs baseline: 1.1377x; 1.1377x over previous
//
#include <hip/hip_runtime.h>
#include <hip/hip_bf16.h>

// Problem constants (fixed by reference)
#define NN 100000
#define EE 1600000
#define HH 128
#define NB 391      // buckets = ceil(NN/256)
#define CAP 5120    // padded bucket capacity (mean 4096, sigma 64 -> +16 sigma)
#define GB 1563     // gemm blocks = ceil(NN/64)

typedef short bf16x8 __attribute__((ext_vector_type(8)));
typedef short bf16x4 __attribute__((ext_vector_type(4)));
typedef float f32x4  __attribute__((ext_vector_type(4)));

__device__ inline short f2bf(float v) {
    __hip_bfloat16 b = __float2bfloat16(v);
    return *reinterpret_cast<short*>(&b);
}

// ---------------------------------------------------------------------------
// Launch 1: weight prep (blocks 0..127) + zero bucket cursors (block 128)
// ---------------------------------------------------------------------------
__global__ __launch_bounds__(1024) void prep_kernel(
    const float* __restrict__ Wl0, const float* __restrict__ Wr0,
    const float* __restrict__ Wl1, const float* __restrict__ Wr1,
    const float* __restrict__ Wl2, const float* __restrict__ Wr2,
    __hip_bfloat16* __restrict__ WT0, __hip_bfloat16* __restrict__ WT1,
    __hip_bfloat16* __restrict__ WT2, int* __restrict__ bcur) {
    const int t = threadIdx.x;
    if (blockIdx.x == 128) {
        if (t < NB) bcur[t] = 0;
        return;
    }
    int id = blockIdx.x * 1024 + t;              // 0 .. 131071
    if (id < 65536) {                            // layer 0: K=256
        int k = id & 255, n = id >> 8;
        float v = (n < 128) ? Wl0[(size_t)k * 128 + n]
                            : Wr0[(size_t)k * 128 + (n - 128)];
        WT0[(size_t)n * 256 + k] = __float2bfloat16(v);
    } else {
        id -= 65536;
        int layer = id >> 15;                    // 0 -> L1, 1 -> L2
        int u = id & 32767;
        int k = u & 127, n = u >> 7;
        const float* Wl = layer ? Wl2 : Wl1;
        const float* Wr = layer ? Wr2 : Wr1;
        __hip_bfloat16* WT = layer ? WT2 : WT1;
        float v = (n < 128) ? Wl[(size_t)k * 128 + n]
                            : Wr[(size_t)k * 128 + (n - 128)];
        WT[(size_t)n * 128 + k] = __float2bfloat16(v);
    }
}

// ---------------------------------------------------------------------------
// MFMA GEMM body (r12 configuration — best measured): [z | r] = h @ [Wl|Wr].
// 64-row tile, single 64x152-half LDS buffer (19.5 KB) reused for staging ->
// z-transpose -> r-transpose. No VGPR cap (r10: cap caused acc spills).
// ~88 VGPR -> 5 blocks/CU. Epilogue: acc -> LDS [node][feature] ->
// 1KB-sectored cooperative stores (r8: strided 8B stores doubled WRITE).
// r13 (32-row tiles) and r14 (barrier-free, no LDS) both regressed — this
// shape is the local optimum. zout may alias hin (staging reads first).
// ---------------------------------------------------------------------------
#define TSW 152   // LDS row stride in halves (304 B, 16B-aligned)
template <int K, bool FIRST>
__device__ __forceinline__ void gemm_body(
    short* __restrict__ lsh, int bid,
    const __hip_bfloat16* hin,
    const float* __restrict__ x0, const float* __restrict__ x1,
    const float* __restrict__ x2, const float* __restrict__ x3,
    const __hip_bfloat16* __restrict__ wt, const float* __restrict__ bias,
    __hip_bfloat16* zout, __hip_bfloat16* __restrict__ rout) {
    const int t    = threadIdx.x;
    const int w    = t >> 6;
    const int lane = t & 63;
    const int quad = lane >> 4;
    const int l16  = lane & 15;
    const int n0   = bid * 64;

    const __hip_bfloat16* afeat[4];
#pragma unroll
    for (int ft = 0; ft < 4; ++ft)
        afeat[ft] = wt + (size_t)(w * 64 + ft * 16 + l16) * K + quad * 8;

    f32x4 acc[4][4];
#pragma unroll
    for (int ft = 0; ft < 4; ++ft)
#pragma unroll
        for (int nt = 0; nt < 4; ++nt)
            acc[ft][nt] = (f32x4){0.f, 0.f, 0.f, 0.f};

    constexpr int NPASS = K / 128;             // 1 (hidden) or 2 (L0)
#pragma unroll
    for (int pass = 0; pass < NPASS; ++pass) {
        if (FIRST) {
            const float* sA = pass ? x2 : x0;
            const float* sB = pass ? x3 : x1;
#pragma unroll
            for (int u = 0; u < 8; ++u) {      // 64 rows x 32 float4-chunks
                const int id  = u * 256 + t;
                const int row = id >> 5, c4 = (id & 31) * 4;
                int rg = n0 + row; if (rg > NN - 1) rg = NN - 1;
                const float* s = (c4 < 64) ? sA : sB;
                const float4 v = *(const float4*)&s[(size_t)rg * 64 + (c4 & 63)];
                bf16x4 p;
                p[0] = f2bf(v.x); p[1] = f2bf(v.y);
                p[2] = f2bf(v.z); p[3] = f2bf(v.w);
                *(bf16x4*)&lsh[row * TSW + c4] = p;
            }
        } else {
#pragma unroll
            for (int u = 0; u < 4; ++u) {      // 64 rows x 16 bf16x8-chunks
                const int id  = u * 256 + t;
                const int row = id >> 4, c8 = (id & 15) * 8;
                int rg = n0 + row; if (rg > NN - 1) rg = NN - 1;
                const bf16x8 v = *(const bf16x8*)&hin[(size_t)rg * K + c8];
                *(bf16x8*)&lsh[row * TSW + c8] = v;
            }
        }
        __syncthreads();

#pragma unroll
        for (int kcl = 0; kcl < 4; ++kcl) {
            const int kc = pass * 4 + kcl;
            bf16x8 af[4];
#pragma unroll
            for (int ft = 0; ft < 4; ++ft)
                af[ft] = *(const bf16x8*)(afeat[ft] + kc * 32);
            bf16x8 bf[4];
#pragma unroll
            for (int nt = 0; nt < 4; ++nt)
                bf[nt] = *(const bf16x8*)&lsh[(nt * 16 + l16) * TSW + kcl * 32 + quad * 8];
#pragma unroll
            for (int ft = 0; ft < 4; ++ft)
#pragma unroll
                for (int nt = 0; nt < 4; ++nt)
                    acc[ft][nt] = __builtin_amdgcn_mfma_f32_16x16x32_bf16(
                        af[ft], bf[nt], acc[ft][nt], 0, 0, 0);
        }
        __syncthreads();
    }

    // z: waves 0,1 transpose (D: col=lane&15=node, row=quad*4+reg=feature)
    if (w < 2) {
#pragma unroll
        for (int ft = 0; ft < 4; ++ft) {
            const int fb = ft * 16 + quad * 4;
#pragma unroll
            for (int nt = 0; nt < 4; ++nt) {
                const f32x4 a = acc[ft][nt];
                bf16x4 p;
                p[0] = f2bf(a[0]); p[1] = f2bf(a[1]);
                p[2] = f2bf(a[2]); p[3] = f2bf(a[3]);
                *(bf16x4*)&lsh[(nt * 16 + l16) * TSW + w * 64 + fb] = p;
            }
        }
    }
    __syncthreads();
#pragma unroll
    for (int u = 0; u < 4; ++u) {              // 16 lanes = one 256B node row
        const int id  = u * 256 + t;
        const int row = id >> 4, ch = (id & 15) * 8;
        const int nd  = n0 + row;
        if (nd < NN)
            *(bf16x8*)&zout[(size_t)nd * HH + ch] = *(const bf16x8*)&lsh[row * TSW + ch];
    }
    __syncthreads();

    // r: waves 2,3 transpose with bias folded
    if (w >= 2) {
        const int fcol = (w - 2) * 64;
#pragma unroll
        for (int ft = 0; ft < 4; ++ft) {
            const int fb = ft * 16 + quad * 4;
            const float4 bv = *(const float4*)&bias[fcol + fb];
#pragma unroll
            for (int nt = 0; nt < 4; ++nt) {
                const f32x4 a = acc[ft][nt];
                bf16x4 p;
                p[0] = f2bf(a[0] + bv.x); p[1] = f2bf(a[1] + bv.y);
                p[2] = f2bf(a[2] + bv.z); p[3] = f2bf(a[3] + bv.w);
                *(bf16x4*)&lsh[(nt * 16 + l16) * TSW + fcol + fb] = p;
            }
        }
    }
    __syncthreads();
#pragma unroll
    for (int u = 0; u < 4; ++u) {
        const int id  = u * 256 + t;
        const int row = id >> 4, ch = (id & 15) * 8;
        const int nd  = n0 + row;
        if (nd < NN)
            *(bf16x8*)&rout[(size_t)nd * HH + ch] = *(const bf16x8*)&lsh[row * TSW + ch];
    }
}

// plain gemm kernel (layers 1,2)
template <int K, bool FIRST>
__global__ __launch_bounds__(256) void gemm_kernel(
    const __hip_bfloat16* hin,
    const float* __restrict__ x0, const float* __restrict__ x1,
    const float* __restrict__ x2, const float* __restrict__ x3,
    const __hip_bfloat16* __restrict__ wt, const float* __restrict__ bias,
    __hip_bfloat16* zout, __hip_bfloat16* __restrict__ rout) {
    __shared__ short lsh[64 * TSW];
    gemm_body<K, FIRST>(lsh, blockIdx.x, hin, x0, x1, x2, x3, wt, bias, zout, rout);
}

// ---------------------------------------------------------------------------
// Launch 2: gemm L0 (blocks [0,GB)) + edge scatter (blocks [GB, GB+NB)).
// Scatter is independent of gemm L0 -> overlaps its ~35 us under L0's ~67 us
// instead of serializing on the critical path (round-15 change).
// Scatter (256 thr): LDS hist over 391 buckets -> global reservation ->
// placement of packed (src<<8)|dstLow within the bucket's padded region.
// ---------------------------------------------------------------------------
__global__ __launch_bounds__(256) void gemm0_scatter_kernel(
    const float* __restrict__ x0, const float* __restrict__ x1,
    const float* __restrict__ x2, const float* __restrict__ x3,
    const __hip_bfloat16* __restrict__ wt, const float* __restrict__ bias,
    __hip_bfloat16* __restrict__ zout, __hip_bfloat16* __restrict__ rout,
    const int* __restrict__ srcv, const int* __restrict__ dstv,
    int* __restrict__ bcur, int* __restrict__ pairs) {
    __shared__ short lsh[64 * TSW];            // gemm: 19.5KB; scatter aliases 3.1KB
    const int t = threadIdx.x;

    if (blockIdx.x < GB) {
        gemm_body<256, true>(lsh, blockIdx.x, nullptr, x0, x1, x2, x3,
                             wt, bias, zout, rout);
        return;
    }

    int* hist = (int*)lsh;
    int* base = hist + NB;
    for (int j = t; j < NB; j += 256) hist[j] = 0;
    __syncthreads();

    const int e0 = (blockIdx.x - GB) * 4096;
    int s[16], d[16];
#pragma unroll
    for (int u = 0; u < 16; ++u) {
        const int e = e0 + u * 256 + t;
        if (e < EE) {
            s[u] = srcv[e]; d[u] = dstv[e];
            atomicAdd(&hist[d[u] >> 8], 1);
        } else {
            d[u] = -1;
        }
    }
    __syncthreads();

    for (int j = t; j < NB; j += 256)
        base[j] = hist[j] ? atomicAdd(&bcur[j], hist[j]) : 0;
    __syncthreads();
    for (int j = t; j < NB; j += 256) hist[j] = base[j];   // reuse as cursor
    __syncthreads();

#pragma unroll
    for (int u = 0; u < 16; ++u)
        if (d[u] >= 0) {
            const int b   = d[u] >> 8;
            const int pos = atomicAdd(&hist[b], 1);
            if (pos < CAP) pairs[b * CAP + pos] = (s[u] << 8) | (d[u] & 255);
        }
}

// ---------------------------------------------------------------------------
// Phase 2: per-bucket counting sort -> csr grouped by node + beg/end/inv.
// ---------------------------------------------------------------------------
__global__ __launch_bounds__(256) void finalize_kernel(
    const int* __restrict__ bcur, const int* __restrict__ pairs,
    int* __restrict__ csr, int* __restrict__ beg, int* __restrict__ eend,
    float* __restrict__ inv) {
    __shared__ int cnt[256];
    __shared__ int scn[256];
    __shared__ int cur[256];
    const int b = blockIdx.x, t = threadIdx.x;
    int m = bcur[b];
    if (m > CAP) m = CAP;

    cnt[t] = 0;
    __syncthreads();
    for (int e = t; e < m; e += 256)
        atomicAdd(&cnt[pairs[b * CAP + e] & 255], 1);
    __syncthreads();

    const int v = cnt[t];
    scn[t] = v;
    __syncthreads();
    for (int st = 1; st < 256; st <<= 1) {
        int tv = (t >= st) ? scn[t - st] : 0;
        __syncthreads();
        scn[t] += tv;
        __syncthreads();
    }
    const int myStart = scn[t] - v;          // exclusive scan
    cur[t] = myStart;
    __syncthreads();

    for (int e = t; e < m; e += 256) {
        const int pk  = pairs[b * CAP + e];
        const int pos = atomicAdd(&cur[pk & 255], 1);
        csr[b * CAP + pos] = pk >> 8;
    }

    const int node = b * 256 + t;
    if (node < NN) {
        beg[node]  = b * CAP + myStart;
        eend[node] = b * CAP + myStart + v;
        inv[node]  = 1.0f / fmaxf((float)v, 1.0f);
    }
}

// ---------------------------------------------------------------------------
// Aggregation + combine: h_out = relu(mean_{in-edges}(z[src]) + r)
// One wave per node; 4 groups x 16 lanes; 16B loads; 4x unroll -> all ~16
// gathers of a mean-degree node in flight. Butterfly (xor 16,32) at the end.
// LAST: fuse layer-3 projection (h3 in f32 regs -> dot Wl3/Wr3 -> z3/r3).
// ---------------------------------------------------------------------------
template <bool LAST>
__global__ __launch_bounds__(256) void aggregate_kernel(
    const __hip_bfloat16* __restrict__ z, __hip_bfloat16* __restrict__ rio,
    const int* __restrict__ beg, const int* __restrict__ eend,
    const int* __restrict__ csr, const float* __restrict__ inv,
    const float* __restrict__ Wl3, const float* __restrict__ Wr3,
    const float* __restrict__ b3, float* __restrict__ z3,
    float* __restrict__ r3) {
    const int i    = (blockIdx.x * 256 + threadIdx.x) >> 6;
    const int lane = threadIdx.x & 63;
    const int g    = lane >> 4;          // edge slot 0..3
    const int l16  = lane & 15;          // 16B chunk within the z row
    if (i >= NN) return;
    const int b0 = beg[i], e0 = eend[i];

    float acc[8];
#pragma unroll
    for (int j = 0; j < 8; ++j) acc[j] = 0.f;

    int e = b0 + g;
    for (; e + 12 < e0; e += 16) {
        const int s0 = csr[e];
        const int s1 = csr[e + 4];
        const int s2 = csr[e + 8];
        const int s3 = csr[e + 12];
        const bf16x8 z0 = *(const bf16x8*)&z[(size_t)s0 * HH + l16 * 8];
        const bf16x8 z1 = *(const bf16x8*)&z[(size_t)s1 * HH + l16 * 8];
        const bf16x8 z2 = *(const bf16x8*)&z[(size_t)s2 * HH + l16 * 8];
        const bf16x8 z3v = *(const bf16x8*)&z[(size_t)s3 * HH + l16 * 8];
        const __hip_bfloat162* p0 = (const __hip_bfloat162*)&z0;
        const __hip_bfloat162* p1 = (const __hip_bfloat162*)&z1;
        const __hip_bfloat162* p2 = (const __hip_bfloat162*)&z2;
        const __hip_bfloat162* p3 = (const __hip_bfloat162*)&z3v;
#pragma unroll
        for (int j = 0; j < 4; ++j) {
            acc[2 * j]     += __bfloat162float(p0[j].x) + __bfloat162float(p1[j].x)
                            + __bfloat162float(p2[j].x) + __bfloat162float(p3[j].x);
            acc[2 * j + 1] += __bfloat162float(p0[j].y) + __bfloat162float(p1[j].y)
                            + __bfloat162float(p2[j].y) + __bfloat162float(p3[j].y);
        }
    }
    for (; e < e0; e += 4) {
        const int s0 = csr[e];
        const bf16x8 z0 = *(const bf16x8*)&z[(size_t)s0 * HH + l16 * 8];
        const __hip_bfloat162* p0 = (const __hip_bfloat162*)&z0;
#pragma unroll
        for (int j = 0; j < 4; ++j) {
            acc[2 * j]     += __bfloat162float(p0[j].x);
            acc[2 * j + 1] += __bfloat162float(p0[j].y);
        }
    }

#pragma unroll
    for (int j = 0; j < 8; ++j) {
        acc[j] += __shfl_xor(acc[j], 16, 64);
        acc[j] += __shfl_xor(acc[j], 32, 64);
    }

    const float iv = inv[i];
    const int   f  = l16 * 8 + g * 2;
    const __hip_bfloat162 rv = *(const __hip_bfloat162*)&rio[(size_t)i * HH + f];
    const float ox = fmaxf(acc[g * 2]     * iv + __bfloat162float(rv.x), 0.f);
    const float oy = fmaxf(acc[g * 2 + 1] * iv + __bfloat162float(rv.y), 0.f);

    if (!LAST) {
        __hip_bfloat162 o;
        o.x = __float2bfloat16(ox);
        o.y = __float2bfloat16(oy);
        *(__hip_bfloat162*)&rio[(size_t)i * HH + f] = o;
    } else {
        const float2 wl = *(const float2*)&Wl3[f];
        const float2 wr = *(const float2*)&Wr3[f];
        float al = ox * wl.x + oy * wl.y;
        float ar = ox * wr.x + oy * wr.y;
#pragma unroll
        for (int m = 32; m; m >>= 1) {
            al += __shfl_xor(al, m, 64);
            ar += __shfl_xor(ar, m, 64);
        }
        if (lane == 0) {
            z3[i] = al;
            r3[i] = ar + b3[0];
        }
    }
}

// Final: out[i] = sigmoid(mean(z3[src]) + r3[i]); per-block partial sums
__global__ __launch_bounds__(256) void final_kernel(
    const float* __restrict__ z3, const float* __restrict__ r3,
    const int* __restrict__ beg, const int* __restrict__ eend,
    const int* __restrict__ csr, const float* __restrict__ inv,
    float* __restrict__ out, float* __restrict__ partial) {
    __shared__ float red[4];
    const int i    = (blockIdx.x * 256 + threadIdx.x) >> 6;
    const int lane = threadIdx.x & 63;
    const int w    = threadIdx.x >> 6;
    float v = 0.f;
    if (i < NN) {
        const int b0 = beg[i], e0 = eend[i];
        float a = 0.f;
        for (int e = b0 + lane; e < e0; e += 64) a += z3[csr[e]];
#pragma unroll
        for (int m = 32; m; m >>= 1) a += __shfl_xor(a, m, 64);
        const float pre = a * inv[i] + r3[i];
        const float s = 1.f / (1.f + __expf(-pre));
        if (lane == 0) { out[i] = s; v = s; }
    }
    if (lane == 0) red[w] = v;
    __syncthreads();
    if (threadIdx.x == 0)
        partial[blockIdx.x] = red[0] + red[1] + red[2] + red[3];
}

__global__ __launch_bounds__(256) void mean_kernel(const float* __restrict__ partial,
                                                   int nb, float* __restrict__ out) {
    __shared__ float lds[256];
    float s = 0.f;
    for (int i = threadIdx.x; i < nb; i += 256) s += partial[i];
    lds[threadIdx.x] = s;
    __syncthreads();
    for (int st = 128; st; st >>= 1) {
        if (threadIdx.x < st) lds[threadIdx.x] += lds[threadIdx.x + st];
        __syncthreads();
    }
    if (threadIdx.x == 0) out[NN] = lds[0] / (float)NN;
}

// ---------------------------------------------------------------------------
extern "C" void kernel_launch(void* const* d_in, const int* in_sizes, int n_in,
                              void* d_out, int out_size, void* d_ws, size_t ws_size,
                              hipStream_t stream) {
    const float* x    = (const float*)d_in[0];
    const float* diff = (const float*)d_in[1];
    const float* rec  = (const float*)d_in[2];
    const float* hid  = (const float*)d_in[3];
    const int* edge   = (const int*)d_in[4];
    const int* esrc = edge;        // row 0
    const int* edst = edge + EE;   // row 1
    const float* Wl0 = (const float*)d_in[5];
    const float* Wr0 = (const float*)d_in[6];
    const float* b0  = (const float*)d_in[7];
    const float* Wl1 = (const float*)d_in[8];
    const float* Wr1 = (const float*)d_in[9];
    const float* b1  = (const float*)d_in[10];
    const float* Wl2 = (const float*)d_in[11];
    const float* Wr2 = (const float*)d_in[12];
    const float* b2  = (const float*)d_in[13];
    const float* Wl3 = (const float*)d_in[14];
    const float* Wr3 = (const float*)d_in[15];
    const float* b3  = (const float*)d_in[16];
    float* out = (float*)d_out;

    // workspace carve-out (256B aligned) — total ~70 MB
    char* w = (char*)d_ws;
    auto alloc = [&](size_t bytes) -> void* {
        void* p = (void*)w;
        w += (bytes + 255) & ~(size_t)255;
        return p;
    };
    __hip_bfloat16* bufA = (__hip_bfloat16*)alloc((size_t)NN * HH * 2);  // 25.6 MB
    __hip_bfloat16* bufB = (__hip_bfloat16*)alloc((size_t)NN * HH * 2);  // 25.6 MB
    __hip_bfloat16* WT0  = (__hip_bfloat16*)alloc((size_t)256 * 256 * 2);
    __hip_bfloat16* WT1  = (__hip_bfloat16*)alloc((size_t)256 * 128 * 2);
    __hip_bfloat16* WT2  = (__hip_bfloat16*)alloc((size_t)256 * 128 * 2);
    int*   pairs   = (int*)alloc((size_t)NB * CAP * 4);                  // 8.0 MB
    int*   csr     = (int*)alloc((size_t)NB * CAP * 4);                  // 8.0 MB
    int*   bcur    = (int*)alloc((size_t)512 * 4);
    int*   beg     = (int*)alloc((size_t)NN * 4);
    int*   eend    = (int*)alloc((size_t)NN * 4);
    float* inv     = (float*)alloc((size_t)NN * 4);
    float* z3      = (float*)alloc((size_t)NN * 4);
    float* r3      = (float*)alloc((size_t)NN * 4);
    float* partial = (float*)alloc((size_t)25000 * 4);

    const int WB = (NN + 3) / 4;             // 25000 (1 node/wave)

    // Launch 1: weight prep + zero cursors (independent, tiny)
    prep_kernel<<<129, 1024, 0, stream>>>(Wl0, Wr0, Wl1, Wr1, Wl2, Wr2,
                                          WT0, WT1, WT2, bcur);

    // Launch 2: gemm L0 (z -> A, r -> B) OVERLAPPED with edge scatter
    gemm0_scatter_kernel<<<GB + NB, 256, 0, stream>>>(
        x, diff, rec, hid, WT0, b0, bufA, bufB, esrc, edst, bcur, pairs);

    // Launch 3: finalize CSR (needs scatter)
    finalize_kernel<<<NB, 256, 0, stream>>>(bcur, pairs, csr, beg, eend, inv);

    // agg L0: h1 -> B (over r)
    aggregate_kernel<false><<<WB, 256, 0, stream>>>(bufA, bufB, beg, eend, csr, inv,
                                                    nullptr, nullptr, nullptr,
                                                    nullptr, nullptr);

    // L1: h in B; z in-place -> B, r -> A; agg: h2 -> A
    gemm_kernel<128, false><<<GB, 256, 0, stream>>>(bufB, nullptr, nullptr, nullptr, nullptr,
                                                    WT1, b1, bufB, bufA);
    aggregate_kernel<false><<<WB, 256, 0, stream>>>(bufB, bufA, beg, eend, csr, inv,
                                                    nullptr, nullptr, nullptr,
                                                    nullptr, nullptr);

    // L2: h in A; z in-place -> A, r -> B; agg(LAST): fused proj3 -> z3, r3
    gemm_kernel<128, false><<<GB, 256, 0, stream>>>(bufA, nullptr, nullptr, nullptr, nullptr,
                                                    WT2, b2, bufA, bufB);
    aggregate_kernel<true><<<WB, 256, 0, stream>>>(bufA, bufB, beg, eend, csr, inv,
                                                   Wl3, Wr3, b3, z3, r3);

    // final: aggregate scalars, sigmoid + mean
    final_kernel<<<WB, 256, 0, stream>>>(z3, r3, beg, eend, csr, inv, out, partial);
    mean_kernel<<<1, 256, 0, stream>>>(partial, WB, out);
}